// Round 15
// baseline (123.893 us; speedup 1.0000x reference)
//
#include <hip/hip_runtime.h>
#include <hip/hip_bf16.h>
#include <stdint.h>

typedef __bf16 bf16;
typedef __attribute__((ext_vector_type(8)))  __bf16 bf16x8;
typedef __attribute__((ext_vector_type(16))) float  f32x16;
typedef __attribute__((ext_vector_type(4)))  float  f32x4v;
typedef __attribute__((ext_vector_type(2)))  float  f32x2v;

#define F_DIM 256
#define C_DIM 512
#define HID   2048
#define C2    256
#define MROWS 16384

// ws: w1pp 1MB | w2pp 1MB   (B-fragment-packed weights for 32x32x16 MFMA)
// pack: element W[n][k] -> frag=(n>>5)*NKF+(k>>4), lane=((k>>3)&1)<<5|(n&31), e=k&7
//       byte = frag*1024 + lane*16 + e*2     (NKF: W1'=16, W2=128)
static constexpr size_t OFF_W1 = 0;
static constexpr size_t OFF_W2 = 1u << 20;

__device__ __forceinline__ unsigned short bfbits(float f) {
    bf16 h = (bf16)f;
    return __builtin_bit_cast(unsigned short, h);
}

// async global->LDS, 16B/lane; dest = wave-uniform base + lane*16 (HW).
typedef const __attribute__((address_space(1))) unsigned int as1_uint;
typedef __attribute__((address_space(3))) unsigned int as3_uint;
__device__ __forceinline__ void gld_lds16(const void* g, void* l) {
    as1_uint* gp = (as1_uint*)(uintptr_t)g;
    as3_uint* lp = (as3_uint*)(uintptr_t)l;
    __builtin_amdgcn_global_load_lds(gp, lp, 16, 0, 0);
}

#define WAITVM2() asm volatile("s_waitcnt vmcnt(2)" ::: "memory")
#define WAITVM0() asm volatile("s_waitcnt vmcnt(0)" ::: "memory")
#define LGKM0()   asm volatile("s_waitcnt lgkmcnt(0)" ::: "memory")
#define SCHED0()  __builtin_amdgcn_sched_barrier(0)

// ---------------- prep: fold interp into W1 + pack both weights as B-frags ----
__global__ __launch_bounds__(256) void prep_kernel(
    const float* __restrict__ w1, const float* __restrict__ w2,
    bf16* __restrict__ w1pp, bf16* __restrict__ w2pp)
{
    const int blk = blockIdx.x;
    const int t = threadIdx.x;
    if (blk < 2048) {
        int idx = blk * 256 + t;
        int h = idx >> 8, k = idx & 255;
        const float* wrow = w1 + (size_t)h * C_DIM;
        float acc = 0.f;
        int jlo = (k == 0) ? 0 : (int)((float)(k - 1) * (511.0f / 255.0f));
        int jhi = (int)((float)(k + 1) * (511.0f / 255.0f)) + 1;
        if (jhi > 511) jhi = 511;
        for (int j = jlo; j <= jhi; ++j) {
            float pos = (float)j * (255.0f / 511.0f);
            int i0 = (int)pos;
            if (i0 > 254) i0 = 254;
            float w = pos - (float)i0;
            float coef = (i0 == k) ? (1.0f - w) : ((i0 + 1 == k) ? w : 0.0f);
            acc += coef * wrow[j];
        }
        size_t frag = (size_t)(h >> 5) * 16 + (k >> 4);
        size_t lane = (size_t)(((k >> 3) & 1) << 5 | (h & 31));
        w1pp[frag * 512 + lane * 8 + (k & 7)] = (bf16)acc;
    } else {
        int idx2 = (blk - 2048) * 256 + t;     // 0..524287
        int c2 = idx2 >> 11, hid = idx2 & 2047;
        float v = w2[(size_t)c2 * HID + hid];
        size_t frag = (size_t)(c2 >> 5) * 128 + (hid >> 4);
        size_t lane = (size_t)(((hid >> 3) & 1) << 5 | (c2 & 31));
        w2pp[frag * 512 + lane * 8 + (hid & 7)] = (bf16)v;
    }
}

// ---------------- fused: DWT -> [G1 -> GELU -> G2] x 4 pairs -> iDWT ----------
// 512 blocks x 512 thr (8 waves), 32 rows/block, 2 blocks/CU (80KB LDS).
// Weights stream via global_load_lds into per-wave PRIVATE 4-slot LDS rings with
// DISTANCE-3 discipline: step u retires frag u (vmcnt(2)), reads slot u&3, and
// refills frag u+3 into slot (u+3)&3 -- a slot whose previous read completed one
// full iteration earlier (no read/overwrite race; round-14 bug fixed). Ring is
// chained across all phases, never drained inside the loop (T4).
__global__ __launch_bounds__(512, 4) void fused_mlp(
    const bf16* __restrict__ w1pp, const bf16* __restrict__ w2pp,
    const float* __restrict__ b1, const float* __restrict__ b2,
    const float* __restrict__ x, float* __restrict__ out)
{
    __shared__ __align__(16) char smem[81920];
    // [0,16K) ll A-frags | [16K,48K) Hs A-frags | [48K,80K) rings (4KB/wave)
    char* hsm = smem + 16384;

    const int tid = threadIdx.x;
    const int l   = tid & 63;
    const int wv  = tid >> 6;          // 0..7
    const int sub = wv >> 2;           // 0..1
    const int sl4 = wv & 3;            // 0..3
    const int R0  = blockIdx.x * 32;
    char* ringb = smem + 49152 + wv * 4096;
    const size_t loff = (size_t)l * 16;
    const char* w1B = (const char*)w1pp;
    const char* w2B = (const char*)w2pp;

    // ---- preload biases (keeps GEMM region free of VGPR-returning VMEM) ----
    float bs[8];
#pragma unroll
    for (int pc = 0; pc < 4; ++pc)
#pragma unroll
        for (int nf = 0; nf < 2; ++nf)
            bs[pc * 2 + nf] = b1[pc * 512 + sub * 256 + sl4 * 64 + nf * 32 + (l & 31)];
    const float b2v = b2[wv * 32 + (l & 31)];

    // ---- ring prologue: pair-0 G1 frags f0,f1,f2 (land under DWT) ----
    // f(u) byte = w1f + (u&1)*16384 + (u>>1)*1024
    {
        const char* w1f = w1B + (size_t)(sub * 8 + sl4 * 2) * 16384 + loff;
        gld_lds16(w1f,          ringb + 0 * 1024 + loff);   // f0
        gld_lds16(w1f + 16384,  ringb + 1 * 1024 + loff);   // f1
        gld_lds16(w1f + 1024,   ringb + 2 * 1024 + loff);   // f2
    }

    // ---- DWT: ll A-frag-packed into LDS (nt x-loads; conflict-free writes) ----
    {
        const int r = tid & 31;
        const int s = tid >> 5;                // 0..15
        const int gbf = R0 + r;
        const float* xr0 = x + ((size_t)(gbf >> 7) * F_DIM + (size_t)(gbf & 127) * 2) * C_DIM;
        const float* xr1 = xr0 + C_DIM;
#pragma unroll
        for (int jj = 0; jj < 2; ++jj) {
            int j = s * 2 + jj;
            f32x4v a[4], b[4];
#pragma unroll
            for (int i = 0; i < 4; ++i) {
                a[i] = __builtin_nontemporal_load((const f32x4v*)(xr0 + (j * 4 + i) * 4));
                b[i] = __builtin_nontemporal_load((const f32x4v*)(xr1 + (j * 4 + i) * 4));
            }
            const float* pa = (const float*)a;
            const float* pb = (const float*)b;
            bf16x8 pk;
#pragma unroll
            for (int e = 0; e < 8; ++e)
                pk[e] = (bf16)(0.5f * (pa[2*e] + pa[2*e+1] + pb[2*e] + pb[2*e+1]));
            *(bf16x8*)(smem + s * 1024 + (size_t)((jj << 5) | r) * 16) = pk;
        }
    }
    __syncthreads();   // full drain: vmcnt baseline 0; ring f0..f2 landed

    f32x16 acc2{};

#pragma unroll
    for (int pc = 0; pc < 4; ++pc) {
        const char* w1f = w1B + (size_t)(pc * 16 + sub * 8 + sl4 * 2) * 16384 + loff;
        const char* w2f = w2B + (size_t)(wv * 128 + pc * 32) * 1024 + loff;
        const char* nx1 = (pc < 3)
            ? w1B + (size_t)((pc + 1) * 16 + sub * 8 + sl4 * 2) * 16384 + loff
            : w1B + loff;              // dummy (drained after loop)

        // ===== GEMM1: 32 steps, 1 ring frag each; af reused over u pairs =====
        f32x16 acc1_0{}, acc1_1{};
        bf16x8 af;
#pragma unroll
        for (int u = 0; u < 32; ++u) {
            WAITVM2();                 // retire frag u (2 newer stay in flight)
            SCHED0();
            if ((u & 1) == 0)
                af = *(const bf16x8*)(smem + (u >> 1) * 1024 + loff);
            bf16x8 wfr = *(const bf16x8*)(ringb + (u & 3) * 1024 + loff);
            if (u < 29) {              // refill frag u+3 -> slot (u+3)&3
                gld_lds16(w1f + ((u + 3) & 1) * 16384 + ((u + 3) >> 1) * 1024,
                          ringb + ((u + 3) & 3) * 1024 + loff);
            } else {                   // chain: this pair's G2 g0,g1,g2
                gld_lds16(w2f + (u - 29) * 1024, ringb + ((u + 3) & 3) * 1024 + loff);
            }
            if (u & 1) acc1_1 = __builtin_amdgcn_mfma_f32_32x32x16_bf16(af, wfr, acc1_1, 0, 0, 0);
            else       acc1_0 = __builtin_amdgcn_mfma_f32_32x32x16_bf16(af, wfr, acc1_0, 0, 0, 0);
        }

        // ===== GELU(+bias) -> Hs (A-frag-packed; DPP lane^1 pair pack) =====
#pragma unroll
        for (int nf = 0; nf < 2; ++nf) {
            const f32x16& A = nf ? acc1_1 : acc1_0;
            const int cin = sub * 256 + sl4 * 64 + nf * 32 + (l & 31);
            const float bsv = bs[pc * 2 + nf];
            const int kf2 = cin >> 4;
#pragma unroll
            for (int reg = 0; reg < 16; ++reg) {
                float v = A[reg] + bsv;
                float tt = v * (0.79788456080f + 0.03567740814f * v * v);
                float g = v / (1.0f + __expf(-2.0f * tt));
                float gp = __builtin_bit_cast(float,
                    __builtin_amdgcn_mov_dpp(__builtin_bit_cast(int, g), 0xB1, 0xF, 0xF, true));
                if (!(l & 1)) {
                    unsigned u = (unsigned)bfbits(g) | ((unsigned)bfbits(gp) << 16);
                    int crow = (reg & 3) + 8 * (reg >> 2) + 4 * (l >> 5);
                    int lane2 = (((l >> 3) & 1) << 5) | crow;
                    *(unsigned*)(hsm + kf2 * 1024 + lane2 * 16 + (l & 7) * 2) = u;
                }
            }
        }
        SCHED0(); LGKM0();             // Hs writes retired
        __builtin_amdgcn_s_barrier();  // raw barrier: ring loads stay in flight
        SCHED0();

        // ===== GEMM2: 32 steps, acc2 += Hs x W2 =====
#pragma unroll
        for (int v = 0; v < 32; ++v) {
            WAITVM2();                 // retire frag g(v)
            SCHED0();
            bf16x8 hf  = *(const bf16x8*)(hsm + v * 1024 + loff);
            bf16x8 wfr = *(const bf16x8*)(ringb + (v & 3) * 1024 + loff);
            if (v < 29) {              // refill g(v+3) -> slot (v+3)&3
                gld_lds16(w2f + (v + 3) * 1024, ringb + ((v + 3) & 3) * 1024 + loff);
            } else {                   // chain: next pair's f0,f1,f2 (pc=3: dummy)
                int u = v - 29;
                gld_lds16(nx1 + (u & 1) * 16384 + (u >> 1) * 1024,
                          ringb + ((v + 3) & 3) * 1024 + loff);
            }
            acc2 = __builtin_amdgcn_mfma_f32_32x32x16_bf16(hf, wfr, acc2, 0, 0, 0);
        }
        SCHED0(); LGKM0();             // Hs reads retired before next GELU overwrite
        __builtin_amdgcn_s_barrier();
        SCHED0();
    }
    WAITVM0();                         // drain dummy ring loads

    // ---- epilogue: bias + iDWT  (out = x + 0.5*(ll_new - ll_old)), nt I/O ----
    {
        const int c2 = wv * 32 + (l & 31);
#pragma unroll
        for (int reg = 0; reg < 16; ++reg) {
            int R = R0 + (reg & 3) + 8 * (reg >> 2) + 4 * (l >> 5);
            int b = R >> 7, f2 = R & 127;
            const float* xr = x + ((size_t)b * F_DIM + (size_t)f2 * 2) * C_DIM;
            f32x2v p0 = __builtin_nontemporal_load((const f32x2v*)(xr + c2 * 2));
            f32x2v p1 = __builtin_nontemporal_load((const f32x2v*)(xr + C_DIM + c2 * 2));
            float llo = 0.5f * (p0[0] + p0[1] + p1[0] + p1[1]);
            float d = 0.5f * ((acc2[reg] + b2v) - llo);
            f32x2v o0, o1;
            o0[0] = p0[0] + d; o0[1] = p0[1] + d;
            o1[0] = p1[0] + d; o1[1] = p1[1] + d;
            float* orow = out + ((size_t)b * F_DIM + (size_t)f2 * 2) * C_DIM;
            __builtin_nontemporal_store(o0, (f32x2v*)(orow + c2 * 2));
            __builtin_nontemporal_store(o1, (f32x2v*)(orow + C_DIM + c2 * 2));
        }
    }
}

extern "C" void kernel_launch(void* const* d_in, const int* in_sizes, int n_in,
                              void* d_out, int out_size, void* d_ws, size_t ws_size,
                              hipStream_t stream) {
    const float* x     = (const float*)d_in[0];
    const float* fc1_w = (const float*)d_in[1];
    const float* fc1_b = (const float*)d_in[2];
    const float* fc2_w = (const float*)d_in[3];
    const float* fc2_b = (const float*)d_in[4];
    float* out = (float*)d_out;

    char* ws = (char*)d_ws;
    bf16* w1pp = (bf16*)(ws + OFF_W1);
    bf16* w2pp = (bf16*)(ws + OFF_W2);

    prep_kernel<<<4096, 256, 0, stream>>>(fc1_w, fc2_w, w1pp, w2pp);
    fused_mlp<<<MROWS / 32, 512, 0, stream>>>(w1pp, w2pp, fc1_b, fc2_b, x, out);
}